// Round 4
// baseline (186.567 us; speedup 1.0000x reference)
//
#include <hip/hip_runtime.h>
#include <hip/hip_bf16.h>

// MHSA: hidden[2,2048,1024], mask[2,2048] i32, W_qkv[16,1024,192] -> out[2,2048,1024]
// f32-or-bf16 inputs (per-block runtime detection in k_cvt_x). Pipeline:
// cvt X->bf16 (into d_out), QKV GEMM (global_load_lds + XOR-swizzled LDS),
// flash attention rebuilt around 32x32x16 MFMA (LDS-pipe was the bottleneck:
// ~84% of iter cycles were ds_read/ds_write):
//   - each wave owns 32 q-rows -> K/V fragments amortize over 2x FLOPs
//   - S^T tiles 32jx32q; C-layout (col=lane&31,row=(reg&3)+8(reg>>2)+4hi)
//   - P never touches LDS: exp2 -> pack pairs -> v_permlane32_swap_b32 gives
//     every lane both hi-half versions (swap semantics: VDST.row1<->VSRC.row0,
//     so with duplicated inputs the FIRST output is the lanes0-31 (hi_src=0)
//     version broadcast, the SECOND is the hi_src=1 version -- round-2 had
//     these two swapped, which permuted P's 8-j halves vs V).
//   - TRIPLE-buffered async K/V staging, raw s_barrier + manual vmcnt(4).

#define NH   16
#define HD   64
#define SEQ  2048
#define HID  1024
#define E3   192
#define QSCALE 0.04508422017f     // (1/32) * log2(e)
#define MBIAS  -43.2808512f       // -30 * log2(e)

typedef __attribute__((ext_vector_type(8))) short short8;
typedef __attribute__((ext_vector_type(4))) float f32x4;
typedef __attribute__((ext_vector_type(16))) float f32x16;
typedef unsigned short ushort_t;

#define MFMA16(a, b, c) __builtin_amdgcn_mfma_f32_16x16x32_bf16((a), (b), (c), 0, 0, 0)
#define MFMA32(a, b, c) __builtin_amdgcn_mfma_f32_32x32x16_bf16((a), (b), (c), 0, 0, 0)

#if __has_builtin(__builtin_amdgcn_exp2f)
#define EXP2(x) __builtin_amdgcn_exp2f(x)
#else
#define EXP2(x) exp2f(x)
#endif

static __device__ __forceinline__ ushort_t f2bf(float x) {
    unsigned u = __builtin_bit_cast(unsigned, x);
    unsigned r = u + 0x7fff + ((u >> 16) & 1);   // RNE
    return (ushort_t)(r >> 16);
}

static __device__ __forceinline__ unsigned pack_trunc(float hi, float lo) {
#if __has_builtin(__builtin_amdgcn_perm)
    return __builtin_amdgcn_perm(__builtin_bit_cast(unsigned, hi),
                                 __builtin_bit_cast(unsigned, lo), 0x07060302u);
#else
    return (__builtin_bit_cast(unsigned, hi) & 0xffff0000u) |
           (__builtin_bit_cast(unsigned, lo) >> 16);
#endif
}

// async global->LDS, 16B/lane; lds dest = wave-uniform base + lane*16
static __device__ __forceinline__ void load_lds16(const void* g, void* l) {
    __builtin_amdgcn_global_load_lds(
        (__attribute__((address_space(1))) void*)(g),
        (__attribute__((address_space(3))) void*)(l), 16, 0, 0);
}

// ---------------------------------------------------------------------------
// Kernel X: X (f32 or bf16) -> Xb bf16 [4096,1024] (Xb lives in d_out).
// ---------------------------------------------------------------------------
__global__ __launch_bounds__(256) void k_cvt_x(const void* __restrict__ Xv,
                                               ushort_t* __restrict__ Xb,
                                               int* __restrict__ flagp) {
    __shared__ int cnt;
    if (threadIdx.x == 0) cnt = 0;
    __syncthreads();
    const unsigned* X32 = (const unsigned*)Xv;
    if (threadIdx.x < 64) {
        unsigned u = X32[(size_t)blockIdx.x * 2048 + threadIdx.x * 32 + 7];
        int bexp = (u >> 7) & 0xFF;
        if (bexp >= 0x68 && bexp <= 0x90) atomicAdd(&cnt, 1);
    }
    __syncthreads();
    const int isf32 = (cnt < 32);
    if (blockIdx.x == 0 && threadIdx.x == 0) *flagp = isf32;

    const size_t base = ((size_t)blockIdx.x * 256 + threadIdx.x) * 16;
    if (isf32) {
        const float* Xf = (const float*)Xv;
        ushort_t tmp[16];
#pragma unroll
        for (int c = 0; c < 4; ++c) {
            float4 v = *(const float4*)(Xf + base + c * 4);
            tmp[c * 4 + 0] = f2bf(v.x); tmp[c * 4 + 1] = f2bf(v.y);
            tmp[c * 4 + 2] = f2bf(v.z); tmp[c * 4 + 3] = f2bf(v.w);
        }
        *(float4*)(Xb + base)     = ((const float4*)tmp)[0];
        *(float4*)(Xb + base + 8) = ((const float4*)tmp)[1];
    } else {
        const ushort_t* Xh = (const ushort_t*)Xv;
        *(float4*)(Xb + base)     = *(const float4*)(Xh + base);
        *(float4*)(Xb + base + 8) = *(const float4*)(Xh + base + 8);
    }
}

// ---------------------------------------------------------------------------
// Kernel A: W_qkv [h][D][e] (f32 or bf16) -> Wt [h*192+e][D] bf16 (3072 x 1024)
// ---------------------------------------------------------------------------
__global__ __launch_bounds__(256) void k_cvt_w(const void* __restrict__ Wv,
                                               ushort_t* __restrict__ Wt,
                                               const int* __restrict__ flagp) {
    __shared__ ushort_t tile[64][72];
    const int isf32 = *flagp;
    const int h  = blockIdx.x;
    const int dt = blockIdx.y;
    const int et = blockIdx.z;
    const int D0 = dt * 64, e0 = et * 64;
    const int t  = threadIdx.x;
#pragma unroll
    for (int r = 0; r < 2; ++r) {
        int row = r * 32 + (t >> 3);
        int col = (t & 7) * 8;
        size_t base = ((size_t)(h * HID + D0 + row)) * E3 + e0 + col;
        if (isf32) {
            const float* Wf = (const float*)Wv;
            float4 a = *(const float4*)(Wf + base);
            float4 c = *(const float4*)(Wf + base + 4);
            tile[row][col + 0] = f2bf(a.x); tile[row][col + 1] = f2bf(a.y);
            tile[row][col + 2] = f2bf(a.z); tile[row][col + 3] = f2bf(a.w);
            tile[row][col + 4] = f2bf(c.x); tile[row][col + 5] = f2bf(c.y);
            tile[row][col + 6] = f2bf(c.z); tile[row][col + 7] = f2bf(c.w);
        } else {
            *(float4*)&tile[row][col] = *(const float4*)((const ushort_t*)Wv + base);
        }
    }
    __syncthreads();
#pragma unroll
    for (int r = 0; r < 2; ++r) {
        int erow = r * 32 + (t >> 3);
        int dcol = (t & 7) * 8;
        ushort_t vals[8];
#pragma unroll
        for (int i = 0; i < 8; ++i) vals[i] = tile[dcol + i][erow];
        *(float4*)(Wt + ((size_t)(h * E3 + e0 + erow)) * HID + D0 + dcol) = *(float4*)vals;
    }
}

// ---------------------------------------------------------------------------
// Kernel B: fused QKV GEMM (m97-style, unchanged)
// ---------------------------------------------------------------------------
__global__ __launch_bounds__(256) void k_qkv(const ushort_t* __restrict__ Xb,
                                             const ushort_t* __restrict__ Wt,
                                             ushort_t* __restrict__ Qb,
                                             ushort_t* __restrict__ Kb,
                                             ushort_t* __restrict__ Vtb) {
    __shared__ __align__(16) ushort_t smem[2 * 128 * 64];
    ushort_t* Xl = smem;
    ushort_t* Wl = smem + 128 * 64;

    const int e0 = blockIdx.x * 128;
    const int m0 = blockIdx.y * 128;
    const int b  = m0 >> 11;
    const int n0 = m0 & 2047;
    const int t = threadIdx.x;
    const int w = t >> 6, lane = t & 63, l15 = lane & 15, quad = lane >> 4;
    const int wrow0 = (w & 1) * 64, wcol0 = (w >> 1) * 64;
    const int srow = lane >> 3;
    const int scb  = (lane & 7) ^ srow;

    f32x4 acc[4][4];
#pragma unroll
    for (int i = 0; i < 4; ++i)
#pragma unroll
        for (int j = 0; j < 4; ++j) acc[i][j] = (f32x4){0.f, 0.f, 0.f, 0.f};

    for (int k0 = 0; k0 < HID; k0 += 64) {
        __syncthreads();
#pragma unroll
        for (int cc = 0; cc < 4; ++cc) {
            const int ch  = w * 4 + cc;
            const int row = ch * 8 + srow;
            load_lds16(Xb + (size_t)(m0 + row) * HID + k0 + scb * 8, &Xl[ch * 512]);
            load_lds16(Wt + (size_t)(e0 + row) * HID + k0 + scb * 8, &Wl[ch * 512]);
        }
        __syncthreads();
#pragma unroll
        for (int kh = 0; kh < 2; ++kh) {
            short8 af[4], bfm[4];
#pragma unroll
            for (int i = 0; i < 4; ++i) {
                const int r = wrow0 + i * 16 + l15;
                af[i] = *(const short8*)&Xl[r * 64 + ((kh * 4 + quad) ^ (r & 7)) * 8];
            }
#pragma unroll
            for (int j = 0; j < 4; ++j) {
                const int r = wcol0 + j * 16 + l15;
                bfm[j] = *(const short8*)&Wl[r * 64 + ((kh * 4 + quad) ^ (r & 7)) * 8];
            }
#pragma unroll
            for (int i = 0; i < 4; ++i)
#pragma unroll
                for (int j = 0; j < 4; ++j)
                    acc[i][j] = MFMA16(af[i], bfm[j], acc[i][j]);
        }
    }

    ushort_t* Vbuf = smem;
    __syncthreads();
#pragma unroll
    for (int i = 0; i < 4; ++i) {
#pragma unroll
        for (int j = 0; j < 4; ++j) {
            const int E0v = e0 + wcol0 + j * 16;
            const int hh  = E0v / 192;
            const int r0  = E0v - hh * 192;
            const int bh  = b * NH + hh;
            const int nb  = n0 + wrow0 + i * 16 + quad * 4;
            if (r0 < 64) {
                const int e = r0 + l15;
#pragma unroll
                for (int reg = 0; reg < 4; ++reg)
                    Qb[((size_t)bh * SEQ + nb + reg) * HD + e] = f2bf(acc[i][j][reg] * QSCALE);
            } else if (r0 < 128) {
                const int e = r0 - 64 + l15;
#pragma unroll
                for (int reg = 0; reg < 4; ++reg)
                    Kb[((size_t)bh * SEQ + nb + reg) * HD + e] = f2bf(acc[i][j][reg]);
            } else {
                const int d  = r0 - 128 + l15;
                const int nl = wrow0 + i * 16 + quad * 4;
#pragma unroll
                for (int reg = 0; reg < 4; ++reg)
                    Vbuf[d * 136 + nl + reg] = f2bf(acc[i][j][reg]);
            }
        }
    }
    const int m3 = blockIdx.x % 3;
    if (m3 != 0) {
        __syncthreads();
        const int hv  = (e0 + ((m3 == 1) ? 0 : 64)) / 192;
        const int bhv = b * NH + hv;
        const int dr = t >> 2, part = t & 3;
        size_t dst = ((size_t)bhv * HD + dr) * SEQ + n0 + part * 32;
#pragma unroll
        for (int c = 0; c < 4; ++c) {
            float4 v = *(const float4*)&Vbuf[dr * 136 + part * 32 + c * 8];
            *(float4*)(Vtb + dst + c * 8) = v;
        }
    }
}

// ---------------------------------------------------------------------------
// Kernel C: flash attention, 32x32x16 MFMA, 256 threads, 4 waves x 32 q-rows.
// ---------------------------------------------------------------------------

// per-32j-tile softmax: exp2 + pack row-pairs + permlane32_swap so every lane
// holds both hi-half versions of each packed dword.
// permlane32_swap semantics: VDST.row1 <-> VSRC.row0. With a==b initially:
// after swap, a = hi_src=0 version in ALL lanes, b = hi_src=1 version.
#define SMPACK(sv, h0v, h1v)                                                  \
    {                                                                         \
        _Pragma("unroll")                                                     \
        for (int g = 0; g < 4; ++g) {                                         \
            float p0 = EXP2(sv[4*g+0]); float p1 = EXP2(sv[4*g+1]);           \
            float p2 = EXP2(sv[4*g+2]); float p3 = EXP2(sv[4*g+3]);           \
            l_r += (p0 + p1) + (p2 + p3);                                     \
            unsigned a0 = pack_trunc(p1, p0), a1 = pack_trunc(p3, p2);        \
            unsigned b0 = a0, b1 = a1;                                        \
            asm volatile("v_permlane32_swap_b32 %0, %1" : "+v"(a0), "+v"(b0));\
            asm volatile("v_permlane32_swap_b32 %0, %1" : "+v"(a1), "+v"(b1));\
            h0v[g*2+0] = a0; h1v[g*2+0] = b0;                                 \
            h0v[g*2+1] = a1; h1v[g*2+1] = b1;                                 \
        }                                                                     \
    }

// B-frag of 32x32x16 PV from packed P dwords; GB in {0,2} (compile-time).
// Lane (q=c31, hi) needs j = 16*c13 + 8*hi + e (e=0..7) of the 32-j subtile:
// dwords m=0..3: m<2 -> hi_src=0 (h0v), m>=2 -> hi_src=1 (h1v); group 2*c13+hi.
#define MAKE_PB(dst, h0v, h1v, GB)                                            \
    {                                                                         \
        unsigned w0_ = hi ? h0v[(GB+1)*2+0] : h0v[(GB)*2+0];                  \
        unsigned w1_ = hi ? h0v[(GB+1)*2+1] : h0v[(GB)*2+1];                  \
        unsigned w2_ = hi ? h1v[(GB+1)*2+0] : h1v[(GB)*2+0];                  \
        unsigned w3_ = hi ? h1v[(GB+1)*2+1] : h1v[(GB)*2+1];                  \
        uint4 u_ = {w0_, w1_, w2_, w3_};                                      \
        dst = __builtin_bit_cast(short8, u_);                                 \
    }

__global__ __launch_bounds__(256) void k_attn(const ushort_t* __restrict__ Qb,
                                              const ushort_t* __restrict__ Kb,
                                              const ushort_t* __restrict__ Vtb,
                                              const int* __restrict__ mask,
                                              void* __restrict__ outv,
                                              const int* __restrict__ flagp) {
    __shared__ __align__(16) char smem_raw[57344];
    // bufs: 3 x 16384 B (K 8192 | V 8192); bias at 49152 (8192 B)
    float* biasl = (float*)(smem_raw + 49152);

    const int isf32 = *flagp;
    const int q0 = blockIdx.x * 128;
    const int bh = blockIdx.y;
    const int b  = bh >> 4, h = bh & 15;
    const int t  = threadIdx.x;
    const int w  = t >> 6, lane = t & 63;
    const int c31 = lane & 31, hi = lane >> 5;
    const int srow = lane >> 3;
    const int scb  = (lane & 7) ^ srow;
    const int rx7  = c31 & 7;

    // prologue staging: pair(0)->buf0, pair(1)->buf1 (drained by setup barrier)
#pragma unroll
    for (int tj = 0; tj < 2; ++tj) {
        ushort_t* kb = (ushort_t*)(smem_raw + tj * 16384);
        ushort_t* vb = kb + 4096;
        load_lds16(Kb  + ((size_t)bh * SEQ + tj * 64 + w * 16 + srow)     * HD + scb * 8, &kb[(w * 2 + 0) * 512]);
        load_lds16(Kb  + ((size_t)bh * SEQ + tj * 64 + w * 16 + 8 + srow) * HD + scb * 8, &kb[(w * 2 + 1) * 512]);
        load_lds16(Vtb + ((size_t)bh * HD + w * 16 + srow)     * SEQ + tj * 64 + scb * 8, &vb[(w * 2 + 0) * 512]);
        load_lds16(Vtb + ((size_t)bh * HD + w * 16 + 8 + srow) * SEQ + tj * 64 + scb * 8, &vb[(w * 2 + 1) * 512]);
    }

    int lm = 0;
    for (int i = t; i < SEQ; i += 256) {
        int mv = mask[b * SEQ + i];
        biasl[i] = mv ? 0.0f : MBIAS;
        lm |= (mv == 0);
    }
    // Q fragments: B-frag of 32x32x16 -> lane holds Q[q0+w*32+c31][ds*16+hi*8+e]
    const int qrow = q0 + w * 32 + c31;
    short8 qB[4];
#pragma unroll
    for (int ds = 0; ds < 4; ++ds)
        qB[ds] = *(const short8*)(Qb + ((size_t)bh * SEQ + qrow) * HD + ds * 16 + hi * 8);

    const int use_bias = __syncthreads_or(lm);  // full drain: vmcnt -> 0 here

    f32x16 oa, ob;
#pragma unroll
    for (int i = 0; i < 16; ++i) { oa[i] = 0.f; ob[i] = 0.f; }
    float l_r = 0.f;

    for (int j0 = 0; j0 < SEQ; j0 += 64) {
        const int idx = (j0 >> 6) % 3;
        // retire this tile's pair (4 loads); keep next pair in flight
        if (j0 + 64 < SEQ) { asm volatile("s_waitcnt vmcnt(4)" ::: "memory"); }
        else               { asm volatile("s_waitcnt vmcnt(0)" ::: "memory"); }
        __builtin_amdgcn_s_barrier();           // raw: no compiler vmcnt(0) drain
        asm volatile("" ::: "memory");
        if (j0 + 128 < SEQ) {                   // stage tile j+2 into buf[(idx+2)%3]
            ushort_t* kb2 = (ushort_t*)(smem_raw + ((idx + 2) % 3) * 16384);
            ushort_t* vb2 = kb2 + 4096;
            load_lds16(Kb  + ((size_t)bh * SEQ + j0 + 128 + w * 16 + srow)     * HD + scb * 8, &kb2[(w * 2 + 0) * 512]);
            load_lds16(Kb  + ((size_t)bh * SEQ + j0 + 128 + w * 16 + 8 + srow) * HD + scb * 8, &kb2[(w * 2 + 1) * 512]);
            load_lds16(Vtb + ((size_t)bh * HD + w * 16 + srow)     * SEQ + j0 + 128 + scb * 8, &vb2[(w * 2 + 0) * 512]);
            load_lds16(Vtb + ((size_t)bh * HD + w * 16 + 8 + srow) * SEQ + j0 + 128 + scb * 8, &vb2[(w * 2 + 1) * 512]);
        }
        ushort_t* kb = (ushort_t*)(smem_raw + idx * 16384);
        ushort_t* vb = kb + 4096;

        // ---- S^T tiles (32j x 32q): A = K rows (row=c31, k=d), B = Q ----
        f32x16 s0, s1;
#pragma unroll
        for (int i = 0; i < 16; ++i) { s0[i] = 0.f; s1[i] = 0.f; }
#pragma unroll
        for (int ds = 0; ds < 4; ++ds) {
            short8 kf0 = *(const short8*)&kb[(c31)      * 64 + ((2 * ds + hi) ^ rx7) * 8];
            short8 kf1 = *(const short8*)&kb[(32 + c31) * 64 + ((2 * ds + hi) ^ rx7) * 8];
            s0 = MFMA32(kf0, qB[ds], s0);
            s1 = MFMA32(kf1, qB[ds], s1);
        }
        if (use_bias) {
#pragma unroll
            for (int g = 0; g < 4; ++g) {
                float4 bj0 = *(const float4*)&biasl[j0 +      8 * g + 4 * hi];
                float4 bj1 = *(const float4*)&biasl[j0 + 32 + 8 * g + 4 * hi];
                s0[4*g+0] += bj0.x; s0[4*g+1] += bj0.y; s0[4*g+2] += bj0.z; s0[4*g+3] += bj0.w;
                s1[4*g+0] += bj1.x; s1[4*g+1] += bj1.y; s1[4*g+2] += bj1.z; s1[4*g+3] += bj1.w;
            }
        }

        // ---- softmax + in-register P relayout (no LDS) ----
        unsigned h0a[8], h1a[8], h0b[8], h1b[8];
        SMPACK(s0, h0a, h1a);
        SMPACK(s1, h0b, h1b);

        // ---- PV: o[d][q] += V^T[d][j] * P[j][q], K=16 chunks ----
#pragma unroll
        for (int jt = 0; jt < 2; ++jt) {
#pragma unroll
            for (int c13 = 0; c13 < 2; ++c13) {
                short8 pb;
                if (jt == 0) { MAKE_PB(pb, h0a, h1a, 2 * c13); }
                else         { MAKE_PB(pb, h0b, h1b, 2 * c13); }
                const int cbase = 2 * (jt * 2 + c13) + hi;
                short8 va0 = *(const short8*)&vb[(c31)      * 64 + (cbase ^ rx7) * 8];
                short8 va1 = *(const short8*)&vb[(32 + c31) * 64 + (cbase ^ rx7) * 8];
                oa = MFMA32(va0, pb, oa);
                ob = MFMA32(va1, pb, ob);
            }
        }
    }

    // ---- l reduce (cols = lane&31; halves differ only in hi) ----
    l_r += __shfl_xor(l_r, 32);
    const float rinv = 1.0f / l_r;

    __syncthreads();
    const int qlr = w * 32 + c31;               // 0..127
    const int r = t >> 1, part = t & 1;
    if (!isf32) {
        ushort_t* Ol = (ushort_t*)smem_raw;     // [128][72]
#pragma unroll
        for (int dt = 0; dt < 2; ++dt) {
            const f32x16 ov = dt ? ob : oa;
#pragma unroll
            for (int g = 0; g < 4; ++g) {
                const int d0 = dt * 32 + 8 * g + 4 * hi;
                uint2 u;
                u.x = (unsigned)f2bf(ov[4*g+0] * rinv) | ((unsigned)f2bf(ov[4*g+1] * rinv) << 16);
                u.y = (unsigned)f2bf(ov[4*g+2] * rinv) | ((unsigned)f2bf(ov[4*g+3] * rinv) << 16);
                *(uint2*)&Ol[qlr * 72 + d0] = u;
            }
        }
        __syncthreads();
        ushort_t* outp = (ushort_t*)outv;
        size_t dst = ((size_t)b * SEQ + q0 + r) * HID + h * HD + part * 32;
#pragma unroll
        for (int c = 0; c < 4; ++c)
            *(float4*)(outp + dst + c * 8) = *(const float4*)&Ol[r * 72 + part * 32 + c * 8];
    } else {
        float* Olf = (float*)smem_raw;          // [128][68]
#pragma unroll
        for (int dt = 0; dt < 2; ++dt) {
            const f32x16 ov = dt ? ob : oa;
#pragma unroll
            for (int g = 0; g < 4; ++g) {
                const int d0 = dt * 32 + 8 * g + 4 * hi;
                float4 fv;
                fv.x = ov[4*g+0] * rinv; fv.y = ov[4*g+1] * rinv;
                fv.z = ov[4*g+2] * rinv; fv.w = ov[4*g+3] * rinv;
                *(float4*)&Olf[qlr * 68 + d0] = fv;
            }
        }
        __syncthreads();
        float* outp = (float*)outv;
        size_t dst = ((size_t)b * SEQ + q0 + r) * HID + h * HD + part * 32;
#pragma unroll
        for (int c = 0; c < 8; ++c)
            *(float4*)(outp + dst + c * 4) = *(const float4*)&Olf[r * 68 + part * 32 + c * 4];
    }
}

// ---------------------------------------------------------------------------
extern "C" void kernel_launch(void* const* d_in, const int* in_sizes, int n_in,
                              void* d_out, int out_size, void* d_ws, size_t ws_size,
                              hipStream_t stream) {
    const void* X    = d_in[0];                 // hidden_states [2,2048,1024] f32 or bf16
    const int*  mask = (const int*)d_in[1];     // attention_mask i32 [2,2048]
    const void* W    = d_in[2];                 // W_qkv [16,1024,192] f32 or bf16

    char* ws = (char*)d_ws;
    // ws: Q 8MB | K 8MB | Vt 8MB | Wt 6MB | flag.  Xb (bf16 X) lives in d_out.
    ushort_t* Qb    = (ushort_t*)(ws);
    ushort_t* Kb    = (ushort_t*)(ws + 8388608);
    ushort_t* Vtb   = (ushort_t*)(ws + 16777216);
    ushort_t* Wtb   = (ushort_t*)(ws + 25165824);
    int*      flagp = (int*)(ws + 31457280);
    ushort_t* Xb    = (ushort_t*)d_out;

    k_cvt_x<<<1024, 256, 0, stream>>>(X, Xb, flagp);
    k_cvt_w<<<dim3(16, 16, 3), 256, 0, stream>>>(W, Wtb, flagp);
    k_qkv<<<dim3(24, 32), 256, 0, stream>>>(Xb, Wtb, Qb, Kb, Vtb);
    k_attn<<<dim3(16, 32), 256, 0, stream>>>(Qb, Kb, Vtb, mask, d_out, flagp);
}

// Round 5
// 175.290 us; speedup vs baseline: 1.0643x; 1.0643x over previous
//
#include <hip/hip_runtime.h>
#include <hip/hip_bf16.h>

// MHSA: hidden[2,2048,1024], mask[2,2048] i32, W_qkv[16,1024,192] -> out[2,2048,1024]
// Pipeline: cvt X->bf16 (into d_out), QKV GEMM, flash attention (32x32x16 MFMA,
// in-register P via permlane32_swap). Round-5: k_attn is latency-bound at 18.5%
// occupancy (256-thr blocks) -> split each j-tile across wave PAIRS: 512 thr =
// 4 q-subtiles x 2 j-halves, per-wave work halved, waves/CU doubled to 16.
// Partial (o, l) merged through LDS in epilogue (softmax has no running max ->
// split-j partial sums merge exactly).

#define NH   16
#define HD   64
#define SEQ  2048
#define HID  1024
#define E3   192
#define QSCALE 0.04508422017f     // (1/32) * log2(e)
#define MBIAS  -43.2808512f       // -30 * log2(e)

typedef __attribute__((ext_vector_type(8))) short short8;
typedef __attribute__((ext_vector_type(4))) float f32x4;
typedef __attribute__((ext_vector_type(16))) float f32x16;
typedef unsigned short ushort_t;

#define MFMA16(a, b, c) __builtin_amdgcn_mfma_f32_16x16x32_bf16((a), (b), (c), 0, 0, 0)
#define MFMA32(a, b, c) __builtin_amdgcn_mfma_f32_32x32x16_bf16((a), (b), (c), 0, 0, 0)

#if __has_builtin(__builtin_amdgcn_exp2f)
#define EXP2(x) __builtin_amdgcn_exp2f(x)
#else
#define EXP2(x) exp2f(x)
#endif

static __device__ __forceinline__ ushort_t f2bf(float x) {
    unsigned u = __builtin_bit_cast(unsigned, x);
    unsigned r = u + 0x7fff + ((u >> 16) & 1);   // RNE
    return (ushort_t)(r >> 16);
}

static __device__ __forceinline__ unsigned pack_trunc(float hi, float lo) {
#if __has_builtin(__builtin_amdgcn_perm)
    return __builtin_amdgcn_perm(__builtin_bit_cast(unsigned, hi),
                                 __builtin_bit_cast(unsigned, lo), 0x07060302u);
#else
    return (__builtin_bit_cast(unsigned, hi) & 0xffff0000u) |
           (__builtin_bit_cast(unsigned, lo) >> 16);
#endif
}

// async global->LDS, 16B/lane; lds dest = wave-uniform base + lane*16
static __device__ __forceinline__ void load_lds16(const void* g, void* l) {
    __builtin_amdgcn_global_load_lds(
        (__attribute__((address_space(1))) void*)(g),
        (__attribute__((address_space(3))) void*)(l), 16, 0, 0);
}

// ---------------------------------------------------------------------------
// Kernel X: X (f32 or bf16) -> Xb bf16 [4096,1024] (Xb lives in d_out).
// ---------------------------------------------------------------------------
__global__ __launch_bounds__(256) void k_cvt_x(const void* __restrict__ Xv,
                                               ushort_t* __restrict__ Xb,
                                               int* __restrict__ flagp) {
    __shared__ int cnt;
    if (threadIdx.x == 0) cnt = 0;
    __syncthreads();
    const unsigned* X32 = (const unsigned*)Xv;
    if (threadIdx.x < 64) {
        unsigned u = X32[(size_t)blockIdx.x * 2048 + threadIdx.x * 32 + 7];
        int bexp = (u >> 7) & 0xFF;
        if (bexp >= 0x68 && bexp <= 0x90) atomicAdd(&cnt, 1);
    }
    __syncthreads();
    const int isf32 = (cnt < 32);
    if (blockIdx.x == 0 && threadIdx.x == 0) *flagp = isf32;

    const size_t base = ((size_t)blockIdx.x * 256 + threadIdx.x) * 16;
    if (isf32) {
        const float* Xf = (const float*)Xv;
        ushort_t tmp[16];
#pragma unroll
        for (int c = 0; c < 4; ++c) {
            float4 v = *(const float4*)(Xf + base + c * 4);
            tmp[c * 4 + 0] = f2bf(v.x); tmp[c * 4 + 1] = f2bf(v.y);
            tmp[c * 4 + 2] = f2bf(v.z); tmp[c * 4 + 3] = f2bf(v.w);
        }
        *(float4*)(Xb + base)     = ((const float4*)tmp)[0];
        *(float4*)(Xb + base + 8) = ((const float4*)tmp)[1];
    } else {
        const ushort_t* Xh = (const ushort_t*)Xv;
        *(float4*)(Xb + base)     = *(const float4*)(Xh + base);
        *(float4*)(Xb + base + 8) = *(const float4*)(Xh + base + 8);
    }
}

// ---------------------------------------------------------------------------
// Kernel A: W_qkv [h][D][e] (f32 or bf16) -> Wt [h*192+e][D] bf16 (3072 x 1024)
// ---------------------------------------------------------------------------
__global__ __launch_bounds__(256) void k_cvt_w(const void* __restrict__ Wv,
                                               ushort_t* __restrict__ Wt,
                                               const int* __restrict__ flagp) {
    __shared__ ushort_t tile[64][72];
    const int isf32 = *flagp;
    const int h  = blockIdx.x;
    const int dt = blockIdx.y;
    const int et = blockIdx.z;
    const int D0 = dt * 64, e0 = et * 64;
    const int t  = threadIdx.x;
#pragma unroll
    for (int r = 0; r < 2; ++r) {
        int row = r * 32 + (t >> 3);
        int col = (t & 7) * 8;
        size_t base = ((size_t)(h * HID + D0 + row)) * E3 + e0 + col;
        if (isf32) {
            const float* Wf = (const float*)Wv;
            float4 a = *(const float4*)(Wf + base);
            float4 c = *(const float4*)(Wf + base + 4);
            tile[row][col + 0] = f2bf(a.x); tile[row][col + 1] = f2bf(a.y);
            tile[row][col + 2] = f2bf(a.z); tile[row][col + 3] = f2bf(a.w);
            tile[row][col + 4] = f2bf(c.x); tile[row][col + 5] = f2bf(c.y);
            tile[row][col + 6] = f2bf(c.z); tile[row][col + 7] = f2bf(c.w);
        } else {
            *(float4*)&tile[row][col] = *(const float4*)((const ushort_t*)Wv + base);
        }
    }
    __syncthreads();
#pragma unroll
    for (int r = 0; r < 2; ++r) {
        int erow = r * 32 + (t >> 3);
        int dcol = (t & 7) * 8;
        ushort_t vals[8];
#pragma unroll
        for (int i = 0; i < 8; ++i) vals[i] = tile[dcol + i][erow];
        *(float4*)(Wt + ((size_t)(h * E3 + e0 + erow)) * HID + D0 + dcol) = *(float4*)vals;
    }
}

// ---------------------------------------------------------------------------
// Kernel B: fused QKV GEMM (m97-style, unchanged)
// ---------------------------------------------------------------------------
__global__ __launch_bounds__(256) void k_qkv(const ushort_t* __restrict__ Xb,
                                             const ushort_t* __restrict__ Wt,
                                             ushort_t* __restrict__ Qb,
                                             ushort_t* __restrict__ Kb,
                                             ushort_t* __restrict__ Vtb) {
    __shared__ __align__(16) ushort_t smem[2 * 128 * 64];
    ushort_t* Xl = smem;
    ushort_t* Wl = smem + 128 * 64;

    const int e0 = blockIdx.x * 128;
    const int m0 = blockIdx.y * 128;
    const int b  = m0 >> 11;
    const int n0 = m0 & 2047;
    const int t = threadIdx.x;
    const int w = t >> 6, lane = t & 63, l15 = lane & 15, quad = lane >> 4;
    const int wrow0 = (w & 1) * 64, wcol0 = (w >> 1) * 64;
    const int srow = lane >> 3;
    const int scb  = (lane & 7) ^ srow;

    f32x4 acc[4][4];
#pragma unroll
    for (int i = 0; i < 4; ++i)
#pragma unroll
        for (int j = 0; j < 4; ++j) acc[i][j] = (f32x4){0.f, 0.f, 0.f, 0.f};

    for (int k0 = 0; k0 < HID; k0 += 64) {
        __syncthreads();
#pragma unroll
        for (int cc = 0; cc < 4; ++cc) {
            const int ch  = w * 4 + cc;
            const int row = ch * 8 + srow;
            load_lds16(Xb + (size_t)(m0 + row) * HID + k0 + scb * 8, &Xl[ch * 512]);
            load_lds16(Wt + (size_t)(e0 + row) * HID + k0 + scb * 8, &Wl[ch * 512]);
        }
        __syncthreads();
#pragma unroll
        for (int kh = 0; kh < 2; ++kh) {
            short8 af[4], bfm[4];
#pragma unroll
            for (int i = 0; i < 4; ++i) {
                const int r = wrow0 + i * 16 + l15;
                af[i] = *(const short8*)&Xl[r * 64 + ((kh * 4 + quad) ^ (r & 7)) * 8];
            }
#pragma unroll
            for (int j = 0; j < 4; ++j) {
                const int r = wcol0 + j * 16 + l15;
                bfm[j] = *(const short8*)&Wl[r * 64 + ((kh * 4 + quad) ^ (r & 7)) * 8];
            }
#pragma unroll
            for (int i = 0; i < 4; ++i)
#pragma unroll
                for (int j = 0; j < 4; ++j)
                    acc[i][j] = MFMA16(af[i], bfm[j], acc[i][j]);
        }
    }

    ushort_t* Vbuf = smem;
    __syncthreads();
#pragma unroll
    for (int i = 0; i < 4; ++i) {
#pragma unroll
        for (int j = 0; j < 4; ++j) {
            const int E0v = e0 + wcol0 + j * 16;
            const int hh  = E0v / 192;
            const int r0  = E0v - hh * 192;
            const int bh  = b * NH + hh;
            const int nb  = n0 + wrow0 + i * 16 + quad * 4;
            if (r0 < 64) {
                const int e = r0 + l15;
#pragma unroll
                for (int reg = 0; reg < 4; ++reg)
                    Qb[((size_t)bh * SEQ + nb + reg) * HD + e] = f2bf(acc[i][j][reg] * QSCALE);
            } else if (r0 < 128) {
                const int e = r0 - 64 + l15;
#pragma unroll
                for (int reg = 0; reg < 4; ++reg)
                    Kb[((size_t)bh * SEQ + nb + reg) * HD + e] = f2bf(acc[i][j][reg]);
            } else {
                const int d  = r0 - 128 + l15;
                const int nl = wrow0 + i * 16 + quad * 4;
#pragma unroll
                for (int reg = 0; reg < 4; ++reg)
                    Vbuf[d * 136 + nl + reg] = f2bf(acc[i][j][reg]);
            }
        }
    }
    const int m3 = blockIdx.x % 3;
    if (m3 != 0) {
        __syncthreads();
        const int hv  = (e0 + ((m3 == 1) ? 0 : 64)) / 192;
        const int bhv = b * NH + hv;
        const int dr = t >> 2, part = t & 3;
        size_t dst = ((size_t)bhv * HD + dr) * SEQ + n0 + part * 32;
#pragma unroll
        for (int c = 0; c < 4; ++c) {
            float4 v = *(const float4*)&Vbuf[dr * 136 + part * 32 + c * 8];
            *(float4*)(Vtb + dst + c * 8) = v;
        }
    }
}

// ---------------------------------------------------------------------------
// Kernel C: flash attention, 32x32x16 MFMA, 512 threads =
//   4 q-subtiles (32 q each) x 2 j-halves (32 j each of the 64-j tile).
// Triple-buffered async K/V staging (2 loads/wave/tile -> vmcnt(2)).
// ---------------------------------------------------------------------------

// softmax for one 32j x 32q s-tile: exp2 + pack row-pairs + permlane32_swap.
// permlane32_swap: VDST.row1 <-> VSRC.row0; with duplicated inputs the FIRST
// output = lanes0-31 (hi_src=0) version per q, SECOND = hi_src=1 version.
#define SMPACK(sv, h0v, h1v)                                                  \
    {                                                                         \
        _Pragma("unroll")                                                     \
        for (int g = 0; g < 4; ++g) {                                         \
            float p0 = EXP2(sv[4*g+0]); float p1 = EXP2(sv[4*g+1]);           \
            float p2 = EXP2(sv[4*g+2]); float p3 = EXP2(sv[4*g+3]);           \
            l_r += (p0 + p1) + (p2 + p3);                                     \
            unsigned a0 = pack_trunc(p1, p0), a1 = pack_trunc(p3, p2);        \
            unsigned b0 = a0, b1 = a1;                                        \
            asm volatile("v_permlane32_swap_b32 %0, %1" : "+v"(a0), "+v"(b0));\
            asm volatile("v_permlane32_swap_b32 %0, %1" : "+v"(a1), "+v"(b1));\
            h0v[g*2+0] = a0; h1v[g*2+0] = b0;                                 \
            h0v[g*2+1] = a1; h1v[g*2+1] = b1;                                 \
        }                                                                     \
    }

// B-frag of 32x32x16 PV from packed P dwords; GB in {0,2} (compile-time).
#define MAKE_PB(dst, h0v, h1v, GB)                                            \
    {                                                                         \
        unsigned w0_ = hi ? h0v[(GB+1)*2+0] : h0v[(GB)*2+0];                  \
        unsigned w1_ = hi ? h0v[(GB+1)*2+1] : h0v[(GB)*2+1];                  \
        unsigned w2_ = hi ? h1v[(GB+1)*2+0] : h1v[(GB)*2+0];                  \
        unsigned w3_ = hi ? h1v[(GB+1)*2+1] : h1v[(GB)*2+1];                  \
        uint4 u_ = {w0_, w1_, w2_, w3_};                                      \
        dst = __builtin_bit_cast(short8, u_);                                 \
    }

__global__ __launch_bounds__(512, 4) void k_attn(const ushort_t* __restrict__ Qb,
                                                 const ushort_t* __restrict__ Kb,
                                                 const ushort_t* __restrict__ Vtb,
                                                 const int* __restrict__ mask,
                                                 void* __restrict__ outv,
                                                 const int* __restrict__ flagp) {
    __shared__ __align__(16) char smem_raw[57344];
    // bufs: 3 x 16384 B (K 8192 | V 8192); bias at 49152 (8192 B)
    float* biasl = (float*)(smem_raw + 49152);

    const int isf32 = *flagp;
    const int q0 = blockIdx.x * 128;
    const int bh = blockIdx.y;
    const int b  = bh >> 4, h = bh & 15;
    const int t  = threadIdx.x;
    const int w  = t >> 6, lane = t & 63;
    const int wq = w >> 1, jh = w & 1;          // q-subtile / j-half
    const int c31 = lane & 31, hi = lane >> 5;
    const int srow = lane >> 3;
    const int scb  = (lane & 7) ^ srow;
    const int rx7  = c31 & 7;

    // prologue staging: pair(0)->buf0, pair(1)->buf1; wave w stages chunk w
    // (8 rows) of K and of V per tile.
#pragma unroll
    for (int tj = 0; tj < 2; ++tj) {
        ushort_t* kb = (ushort_t*)(smem_raw + tj * 16384);
        ushort_t* vb = kb + 4096;
        load_lds16(Kb  + ((size_t)bh * SEQ + tj * 64 + w * 8 + srow) * HD + scb * 8, &kb[w * 512]);
        load_lds16(Vtb + ((size_t)bh * HD + w * 8 + srow) * SEQ + tj * 64 + scb * 8, &vb[w * 512]);
    }

    int lm = 0;
    for (int i = t; i < SEQ; i += 512) {
        int mv = mask[b * SEQ + i];
        biasl[i] = mv ? 0.0f : MBIAS;
        lm |= (mv == 0);
    }
    // Q fragments: B-frag of 32x32x16 -> lane holds Q[q0+wq*32+c31][ds*16+hi*8+e]
    const int qrow = q0 + wq * 32 + c31;
    short8 qB[4];
#pragma unroll
    for (int ds = 0; ds < 4; ++ds)
        qB[ds] = *(const short8*)(Qb + ((size_t)bh * SEQ + qrow) * HD + ds * 16 + hi * 8);

    const int use_bias = __syncthreads_or(lm);  // full drain: vmcnt -> 0 here

    const f32x16 z16 = {0.f,0.f,0.f,0.f,0.f,0.f,0.f,0.f,0.f,0.f,0.f,0.f,0.f,0.f,0.f,0.f};
    f32x16 oa = z16, ob = z16;
    float l_r = 0.f;

    const int jrow = jh * 32 + c31;             // this wave's S rows in the tile

    for (int j0 = 0; j0 < SEQ; j0 += 64) {
        const int idx = (j0 >> 6) % 3;
        // retire this tile's pair (2 loads/wave); keep next pair in flight
        if (j0 + 64 < SEQ) { asm volatile("s_waitcnt vmcnt(2)" ::: "memory"); }
        else               { asm volatile("s_waitcnt vmcnt(0)" ::: "memory"); }
        __builtin_amdgcn_s_barrier();           // raw: no compiler vmcnt(0) drain
        asm volatile("" ::: "memory");
        if (j0 + 128 < SEQ) {                   // stage tile j+2 into buf[(idx+2)%3]
            ushort_t* kb2 = (ushort_t*)(smem_raw + ((idx + 2) % 3) * 16384);
            ushort_t* vb2 = kb2 + 4096;
            load_lds16(Kb  + ((size_t)bh * SEQ + j0 + 128 + w * 8 + srow) * HD + scb * 8, &kb2[w * 512]);
            load_lds16(Vtb + ((size_t)bh * HD + w * 8 + srow) * SEQ + j0 + 128 + scb * 8, &vb2[w * 512]);
        }
        ushort_t* kb = (ushort_t*)(smem_raw + idx * 16384);
        ushort_t* vb = kb + 4096;

        // ---- S tile (this wave's 32j x 32q): A = K rows jrow, B = Q ----
        short8 kf0 = *(const short8*)&kb[jrow * 64 + ((0 + hi) ^ rx7) * 8];
        f32x16 s = MFMA32(kf0, qB[0], z16);
#pragma unroll
        for (int ds = 1; ds < 4; ++ds) {
            short8 kf = *(const short8*)&kb[jrow * 64 + ((2 * ds + hi) ^ rx7) * 8];
            s = MFMA32(kf, qB[ds], s);
        }
        if (use_bias) {
#pragma unroll
            for (int g = 0; g < 4; ++g) {
                float4 bj = *(const float4*)&biasl[j0 + jh * 32 + 8 * g + 4 * hi];
                s[4*g+0] += bj.x; s[4*g+1] += bj.y; s[4*g+2] += bj.z; s[4*g+3] += bj.w;
            }
        }

        // ---- softmax + in-register P relayout (no LDS) ----
        unsigned h0[8], h1[8];
        SMPACK(s, h0, h1);

        // ---- PV: o[d][q] += V^T[d][j] * P[j][q] over this wave's 32 j ----
#pragma unroll
        for (int c13 = 0; c13 < 2; ++c13) {
            short8 pb;
            MAKE_PB(pb, h0, h1, 2 * c13);
            const int cbase = 2 * (jh * 2 + c13) + hi;
            short8 va0 = *(const short8*)&vb[(c31)      * 64 + (cbase ^ rx7) * 8];
            short8 va1 = *(const short8*)&vb[(32 + c31) * 64 + (cbase ^ rx7) * 8];
            oa = MFMA32(va0, pb, oa);
            ob = MFMA32(va1, pb, ob);
        }
    }

    // ---- merge j-halves through LDS, then reduce + store ----
    float l_h = l_r + __shfl_xor(l_r, 32);

    __syncthreads();                            // bufs + bias now dead
    float* Obuf = (float*)smem_raw;             // [256 slots][36 f32]
    float* Lbuf = (float*)(smem_raw + 49152);   // [256] f32
    const int slot = (wq * 64 + lane) * 36;
    if (jh == 1) {
#pragma unroll
        for (int g = 0; g < 4; ++g) {
            *(float4*)&Obuf[slot + g * 4]      = (float4){oa[4*g], oa[4*g+1], oa[4*g+2], oa[4*g+3]};
            *(float4*)&Obuf[slot + 16 + g * 4] = (float4){ob[4*g], ob[4*g+1], ob[4*g+2], ob[4*g+3]};
        }
        Lbuf[wq * 64 + lane] = l_h;
    }
    __syncthreads();
    float rinv = 0.f;
    if (jh == 0) {
        const float l_tot = l_h + Lbuf[wq * 64 + lane];
        rinv = 1.0f / l_tot;
#pragma unroll
        for (int g = 0; g < 4; ++g) {
            float4 pa = *(const float4*)&Obuf[slot + g * 4];
            float4 pb4 = *(const float4*)&Obuf[slot + 16 + g * 4];
            oa[4*g] += pa.x; oa[4*g+1] += pa.y; oa[4*g+2] += pa.z; oa[4*g+3] += pa.w;
            ob[4*g] += pb4.x; ob[4*g+1] += pb4.y; ob[4*g+2] += pb4.z; ob[4*g+3] += pb4.w;
        }
    }
    __syncthreads();                            // Obuf reads done before Ol writes

    const int qlr = wq * 32 + c31;              // 0..127
    const int r = t >> 2, part = t & 3;         // final store: 512 threads
    if (!isf32) {
        ushort_t* Ol = (ushort_t*)smem_raw;     // [128][72]
        if (jh == 0) {
#pragma unroll
            for (int dt = 0; dt < 2; ++dt) {
                const f32x16 ov = dt ? ob : oa;
#pragma unroll
                for (int g = 0; g < 4; ++g) {
                    const int d0 = dt * 32 + 8 * g + 4 * hi;
                    uint2 u;
                    u.x = (unsigned)f2bf(ov[4*g+0] * rinv) | ((unsigned)f2bf(ov[4*g+1] * rinv) << 16);
                    u.y = (unsigned)f2bf(ov[4*g+2] * rinv) | ((unsigned)f2bf(ov[4*g+3] * rinv) << 16);
                    *(uint2*)&Ol[qlr * 72 + d0] = u;
                }
            }
        }
        __syncthreads();
        ushort_t* outp = (ushort_t*)outv;
        size_t dst = ((size_t)b * SEQ + q0 + r) * HID + h * HD + part * 16;
        float4 v0 = *(const float4*)&Ol[r * 72 + part * 16];
        float4 v1 = *(const float4*)&Ol[r * 72 + part * 16 + 8];
        *(float4*)(outp + dst)     = v0;
        *(float4*)(outp + dst + 8) = v1;
    } else {
        float* Olf = (float*)smem_raw;          // [128][68]
        if (jh == 0) {
#pragma unroll
            for (int dt = 0; dt < 2; ++dt) {
                const f32x16 ov = dt ? ob : oa;
#pragma unroll
                for (int g = 0; g < 4; ++g) {
                    const int d0 = dt * 32 + 8 * g + 4 * hi;
                    float4 fv;
                    fv.x = ov[4*g+0] * rinv; fv.y = ov[4*g+1] * rinv;
                    fv.z = ov[4*g+2] * rinv; fv.w = ov[4*g+3] * rinv;
                    *(float4*)&Olf[qlr * 68 + d0] = fv;
                }
            }
        }
        __syncthreads();
        float* outp = (float*)outv;
        size_t dst = ((size_t)b * SEQ + q0 + r) * HID + h * HD + part * 16;
#pragma unroll
        for (int c = 0; c < 4; ++c) {
            float4 v = *(const float4*)&Olf[r * 68 + part * 16 + c * 4];
            *(float4*)(outp + dst + c * 4) = v;
        }
    }
}

// ---------------------------------------------------------------------------
extern "C" void kernel_launch(void* const* d_in, const int* in_sizes, int n_in,
                              void* d_out, int out_size, void* d_ws, size_t ws_size,
                              hipStream_t stream) {
    const void* X    = d_in[0];                 // hidden_states [2,2048,1024] f32 or bf16
    const int*  mask = (const int*)d_in[1];     // attention_mask i32 [2,2048]
    const void* W    = d_in[2];                 // W_qkv [16,1024,192] f32 or bf16

    char* ws = (char*)d_ws;
    // ws: Q 8MB | K 8MB | Vt 8MB | Wt 6MB | flag.  Xb (bf16 X) lives in d_out.
    ushort_t* Qb    = (ushort_t*)(ws);
    ushort_t* Kb    = (ushort_t*)(ws + 8388608);
    ushort_t* Vtb   = (ushort_t*)(ws + 16777216);
    ushort_t* Wtb   = (ushort_t*)(ws + 25165824);
    int*      flagp = (int*)(ws + 31457280);
    ushort_t* Xb    = (ushort_t*)d_out;

    k_cvt_x<<<1024, 256, 0, stream>>>(X, Xb, flagp);
    k_cvt_w<<<dim3(16, 16, 3), 256, 0, stream>>>(W, Wtb, flagp);
    k_qkv<<<dim3(24, 32), 256, 0, stream>>>(Xb, Wtb, Qb, Kb, Vtb);
    k_attn<<<dim3(16, 32), 512, 0, stream>>>(Qb, Kb, Vtb, mask, d_out, flagp);
}